// Round 7
// baseline (261.552 us; speedup 1.0000x reference)
//
#include <hip/hip_runtime.h>

// Problem constants (from reference setup_inputs)
#define NATOMS 32768
#define NFEAT 1920
#define HIDDEN 256
#define NSPEC 4
#define NSTRUCT 512
#define BM 128
#define BK 32
#define NBLK 260                 // ceil(33276/128): 4 species each padded to x128
#define MPAD (NBLK * BM)         // 33280

typedef __bf16 bf16x8 __attribute__((ext_vector_type(8)));
typedef float f32x4 __attribute__((ext_vector_type(4)));
typedef float f4v __attribute__((ext_vector_type(4)));
typedef unsigned short us4 __attribute__((ext_vector_type(4)));

// Workspace layout (bytes). W2t/W3t alias W1t (transposed AFTER layer 1).
#define WS_INTS 0                                        // ints[0..3] counts,[4..7] cursors,[8..12] off; bytes 128..191 zero-stub
#define WS_PERM 256
#define WS_W1T (WS_PERM + MPAD * 4)                      // 133376
#define WS_W2T WS_W1T                                    // alias (post-L1)
#define WS_W3T (WS_W2T + NSPEC * HIDDEN * HIDDEN * 2)    // still inside W1t
#define WS_W4T (WS_W1T + NSPEC * HIDDEN * NFEAT * 2)
#define WS_H1  (WS_W4T + 4096)
#define WS_H2  (WS_H1 + (size_t)MPAD * HIDDEN * 2)       // end ~38.1 MB

// counted vmcnt wait (T4): N loads may remain outstanding
#define VMWAIT(N) asm volatile("s_waitcnt vmcnt(" #N ")" ::: "memory")

__device__ __forceinline__ unsigned short f2bf(float f) {
  unsigned int u = __float_as_uint(f);
  u += 0x7fffu + ((u >> 16) & 1u);           // round-to-nearest-even
  return (unsigned short)(u >> 16);
}
__device__ __forceinline__ float bf2f(unsigned short s) {
  return __uint_as_float(((unsigned int)s) << 16);
}
__device__ __forceinline__ float silu_n(float x) {
  return (x / (1.f + __expf(-x))) * 1.6765f; // variance-preserving SiLU
}

// Direct global->LDS async copy, 16 B per lane. LDS dest = uniform base + lane*16.
__device__ __forceinline__ void gll16(const void* g, void* l) {
  __builtin_amdgcn_global_load_lds(
      (const __attribute__((address_space(1))) void*)g,
      (__attribute__((address_space(3))) void*)l, 16, 0, 0);
}

// ---- prep kernels -------------------------------------------------------

__global__ void k_init(int* ints, int* perm, float* out) {
  int i = blockIdx.x * blockDim.x + threadIdx.x;
  if (i < MPAD) perm[i] = -1;
  if (i < NSTRUCT) out[i] = 0.f;
  if (i < 8) ints[i] = 0;
  if (i >= 32 && i < 48) ((float*)ints)[i] = 0.f;   // zero-stub for padded gather rows
}

// Block-aggregated species count: ballots -> LDS -> 4 atomics per block.
__global__ void k_count(const int* __restrict__ species, int* counts) {
  __shared__ int c[NSPEC];
  int tid = threadIdx.x;
  if (tid < NSPEC) c[tid] = 0;
  __syncthreads();
  int s = species[blockIdx.x * 256 + tid];
  int lane = tid & 63;
#pragma unroll
  for (int sp = 0; sp < NSPEC; ++sp) {
    unsigned long long m = __ballot(s == sp);
    if (lane == 0 && m) atomicAdd(&c[sp], __popcll(m));
  }
  __syncthreads();
  if (tid < NSPEC && c[tid]) atomicAdd(&counts[tid], c[tid]);
}

__global__ void k_offsets(int* ints) {
  int* counts = ints;
  int* cursors = ints + 4;
  int* off = ints + 8;
  off[0] = 0;
  for (int s = 0; s < NSPEC; ++s) {
    off[s + 1] = off[s] + ((counts[s] + 127) & ~127);   // pad to BM=128
    cursors[s] = off[s];
  }
}

// Block-aggregated scatter: one range-reserving atomic per (block, species).
__global__ void k_scatter(const int* __restrict__ species, int* ints, int* perm) {
  __shared__ int cnt[4][NSPEC];   // [wave][species]
  __shared__ int base[NSPEC];
  int tid = threadIdx.x;
  int w = tid >> 6, lane = tid & 63;
  int i = blockIdx.x * 256 + tid;
  int s = species[i];
  unsigned long long m0 = __ballot(s == 0);
  unsigned long long m1 = __ballot(s == 1);
  unsigned long long m2 = __ballot(s == 2);
  unsigned long long m3 = __ballot(s == 3);
  if (lane == 0) {
    cnt[w][0] = __popcll(m0);
    cnt[w][1] = __popcll(m1);
    cnt[w][2] = __popcll(m2);
    cnt[w][3] = __popcll(m3);
  }
  __syncthreads();
  if (tid < NSPEC) {
    int t = cnt[0][tid] + cnt[1][tid] + cnt[2][tid] + cnt[3][tid];
    base[tid] = t ? atomicAdd(&ints[4 + tid], t) : 0;
  }
  __syncthreads();
  unsigned long long mm = (s == 0) ? m0 : (s == 1) ? m1 : (s == 2) ? m2 : m3;
  int pos = base[s] + __popcll(mm & ((1ull << lane) - 1ull));
#pragma unroll
  for (int ww = 0; ww < 4; ++ww)
    if (ww < w) pos += cnt[ww][s];
  perm[pos] = i;
}

// f32 [S][K][N] -> bf16 [S][N][K]  (64x64 LDS tiled transpose)
__global__ void k_transpose(const float* __restrict__ src, unsigned short* __restrict__ dst,
                            int K, int N) {
  __shared__ unsigned short T[64][72];
  int ntN = N >> 6, ntK = K >> 6;
  int per = ntK * ntN;
  int b = blockIdx.x;
  int s = b / per, rem = b % per;
  int k0 = (rem / ntN) << 6;
  int n0 = (rem % ntN) << 6;
  int tid = threadIdx.x;
  int r = tid >> 2, cb = (tid & 3) << 4;
  const float* p = src + ((size_t)s * K + k0 + r) * N + n0 + cb;
#pragma unroll
  for (int j = 0; j < 16; j += 4) {
    f4v v = *(const f4v*)(p + j);
#pragma unroll
    for (int e = 0; e < 4; ++e) T[r][cb + j + e] = f2bf(v[e]);
  }
  __syncthreads();
  unsigned short* drow = dst + ((size_t)s * N + n0 + r) * K + k0 + cb;
#pragma unroll
  for (int j = 0; j < 4; ++j) {
    us4 o;
#pragma unroll
    for (int e = 0; e < 4; ++e) o[e] = T[cb + j * 4 + e][r];
    *(us4*)(drow + j * 4) = o;
  }
}

__global__ void k_w4(const float* __restrict__ src, unsigned short* __restrict__ dst) {
  int i = blockIdx.x * 256 + threadIdx.x;   // 4*256 elems
  dst[i] = f2bf(src[i]);
}

// ---- grouped MFMA GEMM layer -------------------------------------------
// X[Mpad x K] @ Wt[sp][256][K] -> H[Mpad x 256], silu_n epilogue.
// 512 thr = 8 waves (2x4 of 64x64); tile BM=128 x BN=256 x BK=32.
// TRIPLE-buffered global_load_lds staging, depth-2 pipeline with COUNTED
// vmcnt (T3/T4): raw s_barrier (no implicit vmcnt(0) drain); per iter t:
//   wait vmcnt(IPT)  [tile t landed; tile t+1 still in flight]
//   s_barrier
//   issue STAGE(tile t+2) into buf (t+2)%3   [its readers finished at t-1]
//   ds_read frags(tile t) + MFMA
// Never drains vmcnt to 0 inside the loop -> loads stream continuously
// instead of barrier-synchronized bursts (round-6 convoy, 6.5K cyc/step).
template <int K, bool AF32>
__global__ __launch_bounds__(512) void k_mlp(
    const float* __restrict__ xf, const unsigned short* __restrict__ xb,
    const unsigned short* __restrict__ Wt, unsigned short* __restrict__ Hout,
    const int* __restrict__ perm, const int* __restrict__ off,
    const float* __restrict__ zs, float scale) {
  // Per buffer: A = f32 128x32 (16 KB) or bf16 128x32 (8 KB); B = bf16 256x32 (16 KB).
  __shared__ __align__(16) unsigned short Asl[AF32 ? 3 * 128 * 64 : 3 * 128 * 32];
  __shared__ __align__(16) unsigned short Bsl[3 * 256 * 32];
  float* af = (float*)Asl;                 // f32 view (AF32)
  unsigned short* ab = Asl;                // bf16 view
  unsigned short* bl = Bsl;

  // XCD-chunked bijective swizzle (m204)
  int nwg = gridDim.x;
  int xcd = blockIdx.x & 7, idx = blockIdx.x >> 3;
  int q = nwg >> 3, r = nwg & 7;
  int lb = (xcd < r ? xcd * (q + 1) : r * (q + 1) + (xcd - r) * q) + idx;

  int rowbase = lb * BM;
  int tid = threadIdx.x;
  int w = tid >> 6, lane = tid & 63;
  int wr = w >> 2, wc = w & 3;             // wave -> (row 0..1, col 0..3) of 64x64

  int sp;
  if (rowbase < off[1]) sp = 0;
  else if (rowbase < off[2]) sp = 1;
  else if (rowbase < off[3]) sp = 2;
  else sp = 3;

  // ---- staging descriptors (per thread, constant over K) ----
  // B tile: 256 rows x 64 B = 16 chunks of 1 KB; wave w stages chunks 2w,2w+1.
  const unsigned short* srcB[2];
  int ldsB[2];
#pragma unroll
  for (int qq = 0; qq < 2; ++qq) {
    int c = w * 2 + qq;
    int row = c * 16 + (lane >> 2);
    int slot = (lane & 3) ^ ((row >> 2) & 3);
    srcB[qq] = Wt + ((size_t)(sp * HIDDEN + row)) * K + slot * 8;
    ldsB[qq] = c * 512;                    // shorts
  }
  // A tile:
  const float* srcA[2];
  const unsigned short* srcA1 = nullptr;
  int ldsA[2], ldsA1 = 0;
  if constexpr (AF32) {
    // 128 rows x 128 B = 16 chunks of 1 KB (8 rows each); wave w: chunks 2w,2w+1.
#pragma unroll
    for (int qq = 0; qq < 2; ++qq) {
      int c = w * 2 + qq;
      int row = c * 8 + (lane >> 3);
      int slot = (lane & 7) ^ (row & 7);
      long as = perm[rowbase + row];
      srcA[qq] = (as >= 0) ? (xf + (size_t)as * K + slot * 4) : nullptr;
      ldsA[qq] = c * 256;                  // floats
    }
  } else {
    // 128 rows x 64 B = 8 chunks of 1 KB (16 rows each); wave w: chunk w.
    int row = w * 16 + (lane >> 2);
    int slot = (lane & 3) ^ ((row >> 2) & 3);
    srcA1 = xb + ((size_t)(rowbase + row)) * K + slot * 8;
    ldsA1 = w * 512;                       // shorts
  }

  // Per-thread loads per tile (FIFO order fixed): AF32 -> A,A,B,B (4); else A,B,B (3).
  auto STAGE = [&](int b, int k0) {
    if constexpr (AF32) {
#pragma unroll
      for (int qq = 0; qq < 2; ++qq) {
        const float* s = srcA[qq] ? srcA[qq] + k0 : zs;
        gll16(s, af + b * 4096 + ldsA[qq]);
      }
    } else {
      gll16(srcA1 + k0, ab + b * 4096 + ldsA1);
    }
#pragma unroll
    for (int qq = 0; qq < 2; ++qq)
      gll16(srcB[qq] + k0, bl + b * 8192 + ldsB[qq]);
  };

  f32x4 zero4 = {0.f, 0.f, 0.f, 0.f};
  f32x4 acc[4][4];
#pragma unroll
  for (int m = 0; m < 4; ++m)
#pragma unroll
    for (int n = 0; n < 4; ++n) acc[m][n] = zero4;

  int lr = lane & 15, lg = lane >> 4;
  constexpr int NT = K / BK;

  STAGE(0, 0);
  STAGE(1, BK);
  int rb = 0, wb = 2;
  for (int t = 0; t < NT; ++t) {
    if (t < NT - 1) {
      if constexpr (AF32) VMWAIT(4); else VMWAIT(3);   // tile t landed, t+1 flying
    } else {
      VMWAIT(0);                                        // final tile
    }
    __builtin_amdgcn_s_barrier();
    if (t + 2 < NT) {
      STAGE(wb, (t + 2) * BK);
      wb = (wb == 2) ? 0 : wb + 1;
    }

    bf16x8 a[4], b[4];
#pragma unroll
    for (int m = 0; m < 4; ++m) {
      int row = wr * 64 + m * 16 + lr;
      if constexpr (AF32) {
        const float* base = af + rb * 4096 + row * 32;
        f4v x0 = *(const f4v*)(base + (((lg << 1) ^ (row & 7)) << 2));
        f4v x1 = *(const f4v*)(base + ((((lg << 1) | 1) ^ (row & 7)) << 2));
        unsigned r01, r23, r45, r67;
        asm("v_cvt_pk_bf16_f32 %0, %1, %2" : "=v"(r01) : "v"(x0[0]), "v"(x0[1]));
        asm("v_cvt_pk_bf16_f32 %0, %1, %2" : "=v"(r23) : "v"(x0[2]), "v"(x0[3]));
        asm("v_cvt_pk_bf16_f32 %0, %1, %2" : "=v"(r45) : "v"(x1[0]), "v"(x1[1]));
        asm("v_cvt_pk_bf16_f32 %0, %1, %2" : "=v"(r67) : "v"(x1[2]), "v"(x1[3]));
        union { unsigned u[4]; bf16x8 v; } cv = {{r01, r23, r45, r67}};
        a[m] = cv.v;
      } else {
        a[m] = *(const bf16x8*)(ab + rb * 4096 + row * 32 +
                                ((lg ^ ((row >> 2) & 3)) << 3));
      }
    }
#pragma unroll
    for (int n = 0; n < 4; ++n) {
      int row = wc * 64 + n * 16 + lr;
      b[n] = *(const bf16x8*)(bl + rb * 8192 + row * 32 +
                              ((lg ^ ((row >> 2) & 3)) << 3));
    }
#pragma unroll
    for (int m = 0; m < 4; ++m)
#pragma unroll
      for (int n = 0; n < 4; ++n)
        acc[m][n] = __builtin_amdgcn_mfma_f32_16x16x32_bf16(a[m], b[n], acc[m][n], 0, 0, 0);

    rb = (rb == 2) ? 0 : rb + 1;
  }

  // epilogue: D[row=wr*64+m*16+lg*4+r][col=wc*64+n*16+lr]
#pragma unroll
  for (int m = 0; m < 4; ++m)
#pragma unroll
    for (int n = 0; n < 4; ++n)
#pragma unroll
      for (int rr = 0; rr < 4; ++rr) {
        float v = acc[m][n][rr] * scale;
        Hout[(size_t)(rowbase + wr * 64 + m * 16 + lg * 4 + rr) * HIDDEN +
             wc * 64 + n * 16 + lr] = f2bf(silu_n(v));
      }
}

// ---- layer 4 + segment reduction ---------------------------------------
__global__ void k_l4(const unsigned short* __restrict__ H3, const unsigned short* __restrict__ W4t,
                     const int* __restrict__ perm, const int* __restrict__ species,
                     const int* __restrict__ sidx, const float* __restrict__ coeff,
                     float* __restrict__ out) {
  int w = threadIdx.x >> 6, l = threadIdx.x & 63;
  int row = blockIdx.x * 4 + w;
  int src = perm[row];
  if (src < 0) return;
  int sp = species[src];
  us4 h = *(const us4*)&H3[(size_t)row * HIDDEN + l * 4];
  us4 wv = *(const us4*)&W4t[sp * HIDDEN + l * 4];
  float sum = 0.f;
#pragma unroll
  for (int e = 0; e < 4; ++e) sum += bf2f(h[e]) * bf2f(wv[e]);
#pragma unroll
  for (int d = 32; d >= 1; d >>= 1) sum += __shfl_xor(sum, d, 64);
  if (l == 0)
    atomicAdd(&out[sidx[src]], sum * (0.0625f * 0.125f) + coeff[sp]);
}

// ---- launcher -----------------------------------------------------------
extern "C" void kernel_launch(void* const* d_in, const int* in_sizes, int n_in,
                              void* d_out, int out_size, void* d_ws, size_t ws_size,
                              hipStream_t stream) {
  const float* features = (const float*)d_in[0];
  const float* W1 = (const float*)d_in[1];
  const float* W2 = (const float*)d_in[2];
  const float* W3 = (const float*)d_in[3];
  const float* W4 = (const float*)d_in[4];
  const float* coeff = (const float*)d_in[5];
  const int* species = (const int*)d_in[6];
  const int* sidx = (const int*)d_in[7];
  float* out = (float*)d_out;

  char* ws = (char*)d_ws;
  int* ints = (int*)(ws + WS_INTS);
  const float* zs = (const float*)(ws + 128);       // zero-stub (16 B used)
  int* perm = (int*)(ws + WS_PERM);
  unsigned short* W1t = (unsigned short*)(ws + WS_W1T);
  unsigned short* W2t = (unsigned short*)(ws + WS_W2T);
  unsigned short* W3t = (unsigned short*)(ws + WS_W3T);
  unsigned short* W4t = (unsigned short*)(ws + WS_W4T);
  unsigned short* H1 = (unsigned short*)(ws + WS_H1);
  unsigned short* H2 = (unsigned short*)(ws + WS_H2);

  // species bucketing
  k_init<<<(MPAD + 255) / 256, 256, 0, stream>>>(ints, perm, out);
  k_count<<<NATOMS / 256, 256, 0, stream>>>(species, ints);
  k_offsets<<<1, 1, 0, stream>>>(ints);
  k_scatter<<<NATOMS / 256, 256, 0, stream>>>(species, ints, perm);

  // weight prep for layer 1 (W2/W3 transposed after L1 — they alias W1t)
  k_transpose<<<NSPEC * (NFEAT / 64) * (HIDDEN / 64), 256, 0, stream>>>(W1, W1t, NFEAT, HIDDEN);
  k_w4<<<NSPEC, 256, 0, stream>>>(W4, W4t);

  const float s1 = 1.f / sqrtf((float)NFEAT);
  const float s2 = 1.f / 16.f;

  // layer 1 (f32 gather -> bf16 MFMA)
  k_mlp<NFEAT, true><<<NBLK, 512, 0, stream>>>(features, nullptr, W1t, H1, perm, ints + 8, zs, s1);

  // W2/W3 prep (W1t region now dead)
  k_transpose<<<NSPEC * (HIDDEN / 64) * (HIDDEN / 64), 256, 0, stream>>>(W2, W2t, HIDDEN, HIDDEN);
  k_transpose<<<NSPEC * (HIDDEN / 64) * (HIDDEN / 64), 256, 0, stream>>>(W3, W3t, HIDDEN, HIDDEN);

  // layers 2, 3
  k_mlp<HIDDEN, false><<<NBLK, 512, 0, stream>>>(nullptr, H1, W2t, H2, perm, ints + 8, zs, s2);
  k_mlp<HIDDEN, false><<<NBLK, 512, 0, stream>>>(nullptr, H2, W3t, H1, perm, ints + 8, zs, s2);

  // layer 4 + segment sum + composition term
  k_l4<<<MPAD / 4, 256, 0, stream>>>(H1, W4t, perm, species, sidx, coeff, out);
}

// Round 8
// 213.153 us; speedup vs baseline: 1.2271x; 1.2271x over previous
//
#include <hip/hip_runtime.h>

// Problem constants (from reference setup_inputs)
#define NATOMS 32768
#define NFEAT 1920
#define HIDDEN 256
#define NSPEC 4
#define NSTRUCT 512
#define BM 64
#define BN 128
#define BK 32
#define MTILES 516               // max 64-row tiles (4 species padded to x64)
#define MPAD (MTILES * BM)       // 33024
#define NBLKG (MTILES * 2)       // 1032 blocks: (m-tile, n-half)

typedef __bf16 bf16x8 __attribute__((ext_vector_type(8)));
typedef float f32x4 __attribute__((ext_vector_type(4)));
typedef float f4v __attribute__((ext_vector_type(4)));
typedef unsigned short us4 __attribute__((ext_vector_type(4)));

// Workspace layout (bytes). W2t/W3t alias W1t (transposed AFTER layer 1).
#define WS_INTS 0                                        // ints[0..3] counts,[4..7] cursors,[8..12] off; bytes 128..191 zero-stub
#define WS_PERM 256
#define WS_W1T (WS_PERM + MPAD * 4)                      // 132352
#define WS_W2T WS_W1T                                    // alias (post-L1)
#define WS_W3T (WS_W2T + NSPEC * HIDDEN * HIDDEN * 2)    // still inside W1t
#define WS_W4T (WS_W1T + NSPEC * HIDDEN * NFEAT * 2)
#define WS_H1  (WS_W4T + 4096)
#define WS_H2  (WS_H1 + (size_t)MPAD * HIDDEN * 2)       // end ~38 MB

__device__ __forceinline__ unsigned short f2bf(float f) {
  unsigned int u = __float_as_uint(f);
  u += 0x7fffu + ((u >> 16) & 1u);           // round-to-nearest-even
  return (unsigned short)(u >> 16);
}
__device__ __forceinline__ float bf2f(unsigned short s) {
  return __uint_as_float(((unsigned int)s) << 16);
}
__device__ __forceinline__ float silu_n(float x) {
  return (x / (1.f + __expf(-x))) * 1.6765f; // variance-preserving SiLU
}

// Direct global->LDS async copy, 16 B per lane. LDS dest = uniform base + lane*16.
__device__ __forceinline__ void gll16(const void* g, void* l) {
  __builtin_amdgcn_global_load_lds(
      (const __attribute__((address_space(1))) void*)g,
      (__attribute__((address_space(3))) void*)l, 16, 0, 0);
}

// ---- prep kernels -------------------------------------------------------

__global__ void k_init(int* ints, int* perm, float* out) {
  int i = blockIdx.x * blockDim.x + threadIdx.x;
  if (i < MPAD) perm[i] = -1;
  if (i < NSTRUCT) out[i] = 0.f;
  if (i < 8) ints[i] = 0;
  if (i >= 32 && i < 48) ((float*)ints)[i] = 0.f;   // zero-stub for padded gather rows
}

// Block-aggregated species count: ballots -> LDS -> 4 atomics per block.
__global__ void k_count(const int* __restrict__ species, int* counts) {
  __shared__ int c[NSPEC];
  int tid = threadIdx.x;
  if (tid < NSPEC) c[tid] = 0;
  __syncthreads();
  int s = species[blockIdx.x * 256 + tid];
  int lane = tid & 63;
#pragma unroll
  for (int sp = 0; sp < NSPEC; ++sp) {
    unsigned long long m = __ballot(s == sp);
    if (lane == 0 && m) atomicAdd(&c[sp], __popcll(m));
  }
  __syncthreads();
  if (tid < NSPEC && c[tid]) atomicAdd(&counts[tid], c[tid]);
}

__global__ void k_offsets(int* ints) {
  int* counts = ints;
  int* cursors = ints + 4;
  int* off = ints + 8;
  off[0] = 0;
  for (int s = 0; s < NSPEC; ++s) {
    off[s + 1] = off[s] + ((counts[s] + 63) & ~63);    // pad to BM=64
    cursors[s] = off[s];
  }
}

// Block-aggregated scatter: one range-reserving atomic per (block, species).
__global__ void k_scatter(const int* __restrict__ species, int* ints, int* perm) {
  __shared__ int cnt[4][NSPEC];   // [wave][species]
  __shared__ int base[NSPEC];
  int tid = threadIdx.x;
  int w = tid >> 6, lane = tid & 63;
  int i = blockIdx.x * 256 + tid;
  int s = species[i];
  unsigned long long m0 = __ballot(s == 0);
  unsigned long long m1 = __ballot(s == 1);
  unsigned long long m2 = __ballot(s == 2);
  unsigned long long m3 = __ballot(s == 3);
  if (lane == 0) {
    cnt[w][0] = __popcll(m0);
    cnt[w][1] = __popcll(m1);
    cnt[w][2] = __popcll(m2);
    cnt[w][3] = __popcll(m3);
  }
  __syncthreads();
  if (tid < NSPEC) {
    int t = cnt[0][tid] + cnt[1][tid] + cnt[2][tid] + cnt[3][tid];
    base[tid] = t ? atomicAdd(&ints[4 + tid], t) : 0;
  }
  __syncthreads();
  unsigned long long mm = (s == 0) ? m0 : (s == 1) ? m1 : (s == 2) ? m2 : m3;
  int pos = base[s] + __popcll(mm & ((1ull << lane) - 1ull));
#pragma unroll
  for (int ww = 0; ww < 4; ++ww)
    if (ww < w) pos += cnt[ww][s];
  perm[pos] = i;
}

// f32 [S][K][N] -> bf16 [S][N][K]  (64x64 LDS tiled transpose)
__global__ void k_transpose(const float* __restrict__ src, unsigned short* __restrict__ dst,
                            int K, int N) {
  __shared__ unsigned short T[64][72];
  int ntN = N >> 6, ntK = K >> 6;
  int per = ntK * ntN;
  int b = blockIdx.x;
  int s = b / per, rem = b % per;
  int k0 = (rem / ntN) << 6;
  int n0 = (rem % ntN) << 6;
  int tid = threadIdx.x;
  int r = tid >> 2, cb = (tid & 3) << 4;
  const float* p = src + ((size_t)s * K + k0 + r) * N + n0 + cb;
#pragma unroll
  for (int j = 0; j < 16; j += 4) {
    f4v v = *(const f4v*)(p + j);
#pragma unroll
    for (int e = 0; e < 4; ++e) T[r][cb + j + e] = f2bf(v[e]);
  }
  __syncthreads();
  unsigned short* drow = dst + ((size_t)s * N + n0 + r) * K + k0 + cb;
#pragma unroll
  for (int j = 0; j < 4; ++j) {
    us4 o;
#pragma unroll
    for (int e = 0; e < 4; ++e) o[e] = T[cb + j * 4 + e][r];
    *(us4*)(drow + j * 4) = o;
  }
}

__global__ void k_w4(const float* __restrict__ src, unsigned short* __restrict__ dst) {
  int i = blockIdx.x * 256 + threadIdx.x;   // 4*256 elems
  dst[i] = f2bf(src[i]);
}

// ---- grouped MFMA GEMM layer -------------------------------------------
// X[Mpad x K] @ Wt[sp][256][K] -> H[Mpad x 256], silu_n epilogue.
// SMALL-TILE / HIGH-OCCUPANCY shape: 256 thr = 4 waves (2x2 of 32x64);
// tile BM=64 x BN=128 x BK=32; grid = MTILES*2 (m-tile, n-half) = 1032 blocks
// (~4/CU -> inter-block latency hiding + near-zero dispatch tail; round 5-7's
// 260/516-block grids paid a 1.5-2x straggler tail).
// Double-buffered global_load_lds staging, drain-style sync (round-6 best).
// LDS linear; XOR slot-swizzle applied BOTH at the per-lane global source
// address and at the ds_read fragment address (rule #21).
template <int K, bool AF32>
__global__ __launch_bounds__(256) void k_mlp(
    const float* __restrict__ xf, const unsigned short* __restrict__ xb,
    const unsigned short* __restrict__ Wt, unsigned short* __restrict__ Hout,
    const int* __restrict__ perm, const int* __restrict__ off,
    const float* __restrict__ zs, float scale) {
  // Per buffer: A = f32 64x32 (8 KB) or bf16 64x32 (4 KB); B = bf16 128x32 (8 KB).
  __shared__ __align__(16) unsigned short Asl[AF32 ? 2 * 64 * 64 : 2 * 64 * 32];
  __shared__ __align__(16) unsigned short Bsl[2 * 128 * 32];
  float* af = (float*)Asl;                 // f32 view (AF32)
  unsigned short* ab = Asl;                // bf16 view
  unsigned short* bl = Bsl;

  // XCD-chunked bijective swizzle (nwg=1032: q=129, r=0). Consecutive lb
  // (same XCD, co-resident) = the two n-halves of one m-tile -> shared A
  // panel hits L2 on the second read.
  int nwg = gridDim.x;
  int xcd = blockIdx.x & 7, idx = blockIdx.x >> 3;
  int q = nwg >> 3, r = nwg & 7;
  int lb = (xcd < r ? xcd * (q + 1) : r * (q + 1) + (xcd - r) * q) + idx;
  int mt = lb >> 1, bn = lb & 1;

  int rowbase = mt * BM;
  int tid = threadIdx.x;
  int w = tid >> 6, lane = tid & 63;
  int wr = w >> 1, wc = w & 1;             // wave -> (row-half, col-half) of 32x64

  int sp;
  if (rowbase < off[1]) sp = 0;
  else if (rowbase < off[2]) sp = 1;
  else if (rowbase < off[3]) sp = 2;
  else sp = 3;

  // ---- staging descriptors (per thread, constant over K) ----
  // B tile: 128 rows x 64 B = 8 chunks of 1 KB; wave w stages chunks 2w,2w+1.
  const unsigned short* srcB[2];
  int ldsB[2];
#pragma unroll
  for (int qq = 0; qq < 2; ++qq) {
    int c = w * 2 + qq;
    int row = c * 16 + (lane >> 2);        // 0..127
    int slot = (lane & 3) ^ ((row >> 2) & 3);
    srcB[qq] = Wt + ((size_t)(sp * HIDDEN + bn * BN + row)) * K + slot * 8;
    ldsB[qq] = c * 512;                    // shorts
  }
  // A tile:
  const float* srcA[2];
  const unsigned short* srcA1 = nullptr;
  int ldsA[2], ldsA1 = 0;
  if constexpr (AF32) {
    // 64 rows x 128 B = 8 chunks of 1 KB (8 rows each); wave w: chunks 2w,2w+1.
#pragma unroll
    for (int qq = 0; qq < 2; ++qq) {
      int c = w * 2 + qq;
      int row = c * 8 + (lane >> 3);       // 0..63
      int slot = (lane & 7) ^ (row & 7);
      long as = perm[rowbase + row];
      srcA[qq] = (as >= 0) ? (xf + (size_t)as * K + slot * 4) : nullptr;
      ldsA[qq] = c * 256;                  // floats
    }
  } else {
    // 64 rows x 64 B = 4 chunks of 1 KB (16 rows each); wave w: chunk w.
    int row = w * 16 + (lane >> 2);        // 0..63
    int slot = (lane & 3) ^ ((row >> 2) & 3);
    srcA1 = xb + ((size_t)(rowbase + row)) * K + slot * 8;
    ldsA1 = w * 512;                       // shorts
  }

  auto STAGE = [&](int b, int k0) {
    if constexpr (AF32) {
#pragma unroll
      for (int qq = 0; qq < 2; ++qq) {
        const float* s = srcA[qq] ? srcA[qq] + k0 : zs;
        gll16(s, af + b * 2048 + ldsA[qq]);
      }
    } else {
      gll16(srcA1 + k0, ab + b * 2048 + ldsA1);
    }
#pragma unroll
    for (int qq = 0; qq < 2; ++qq)
      gll16(srcB[qq] + k0, bl + b * 4096 + ldsB[qq]);
  };

  f32x4 zero4 = {0.f, 0.f, 0.f, 0.f};
  f32x4 acc[2][4];
#pragma unroll
  for (int m = 0; m < 2; ++m)
#pragma unroll
    for (int n = 0; n < 4; ++n) acc[m][n] = zero4;

  int lr = lane & 15, lg = lane >> 4;
  constexpr int NT = K / BK;

  STAGE(0, 0);
  __syncthreads();
  int buf = 0;
  for (int t = 0; t < NT; ++t) {
    if (t + 1 < NT) STAGE(buf ^ 1, (t + 1) * BK);

    bf16x8 a[2], b[4];
#pragma unroll
    for (int m = 0; m < 2; ++m) {
      int row = wr * 32 + m * 16 + lr;
      if constexpr (AF32) {
        const float* base = af + buf * 2048 + row * 32;
        f4v x0 = *(const f4v*)(base + (((lg << 1) ^ (row & 7)) << 2));
        f4v x1 = *(const f4v*)(base + ((((lg << 1) | 1) ^ (row & 7)) << 2));
        unsigned r01, r23, r45, r67;
        asm("v_cvt_pk_bf16_f32 %0, %1, %2" : "=v"(r01) : "v"(x0[0]), "v"(x0[1]));
        asm("v_cvt_pk_bf16_f32 %0, %1, %2" : "=v"(r23) : "v"(x0[2]), "v"(x0[3]));
        asm("v_cvt_pk_bf16_f32 %0, %1, %2" : "=v"(r45) : "v"(x1[0]), "v"(x1[1]));
        asm("v_cvt_pk_bf16_f32 %0, %1, %2" : "=v"(r67) : "v"(x1[2]), "v"(x1[3]));
        union { unsigned u[4]; bf16x8 v; } cv = {{r01, r23, r45, r67}};
        a[m] = cv.v;
      } else {
        a[m] = *(const bf16x8*)(ab + buf * 2048 + row * 32 +
                                ((lg ^ ((row >> 2) & 3)) << 3));
      }
    }
#pragma unroll
    for (int n = 0; n < 4; ++n) {
      int row = wc * 64 + n * 16 + lr;     // 0..127 within B tile
      b[n] = *(const bf16x8*)(bl + buf * 4096 + row * 32 +
                              ((lg ^ ((row >> 2) & 3)) << 3));
    }
#pragma unroll
    for (int m = 0; m < 2; ++m)
#pragma unroll
      for (int n = 0; n < 4; ++n)
        acc[m][n] = __builtin_amdgcn_mfma_f32_16x16x32_bf16(a[m], b[n], acc[m][n], 0, 0, 0);

    __syncthreads();                       // drain (t+1 staged) + barrier
    buf ^= 1;
  }

  // epilogue: D[row=wr*32+m*16+lg*4+rr][col=bn*128+wc*64+n*16+lr]
#pragma unroll
  for (int m = 0; m < 2; ++m)
#pragma unroll
    for (int n = 0; n < 4; ++n)
#pragma unroll
      for (int rr = 0; rr < 4; ++rr) {
        float v = acc[m][n][rr] * scale;
        Hout[(size_t)(rowbase + wr * 32 + m * 16 + lg * 4 + rr) * HIDDEN +
             bn * BN + wc * 64 + n * 16 + lr] = f2bf(silu_n(v));
      }
}

// ---- layer 4 + segment reduction ---------------------------------------
__global__ void k_l4(const unsigned short* __restrict__ H3, const unsigned short* __restrict__ W4t,
                     const int* __restrict__ perm, const int* __restrict__ species,
                     const int* __restrict__ sidx, const float* __restrict__ coeff,
                     float* __restrict__ out) {
  int w = threadIdx.x >> 6, l = threadIdx.x & 63;
  int row = blockIdx.x * 4 + w;
  int src = perm[row];
  if (src < 0) return;
  int sp = species[src];
  us4 h = *(const us4*)&H3[(size_t)row * HIDDEN + l * 4];
  us4 wv = *(const us4*)&W4t[sp * HIDDEN + l * 4];
  float sum = 0.f;
#pragma unroll
  for (int e = 0; e < 4; ++e) sum += bf2f(h[e]) * bf2f(wv[e]);
#pragma unroll
  for (int d = 32; d >= 1; d >>= 1) sum += __shfl_xor(sum, d, 64);
  if (l == 0)
    atomicAdd(&out[sidx[src]], sum * (0.0625f * 0.125f) + coeff[sp]);
}

// ---- launcher -----------------------------------------------------------
extern "C" void kernel_launch(void* const* d_in, const int* in_sizes, int n_in,
                              void* d_out, int out_size, void* d_ws, size_t ws_size,
                              hipStream_t stream) {
  const float* features = (const float*)d_in[0];
  const float* W1 = (const float*)d_in[1];
  const float* W2 = (const float*)d_in[2];
  const float* W3 = (const float*)d_in[3];
  const float* W4 = (const float*)d_in[4];
  const float* coeff = (const float*)d_in[5];
  const int* species = (const int*)d_in[6];
  const int* sidx = (const int*)d_in[7];
  float* out = (float*)d_out;

  char* ws = (char*)d_ws;
  int* ints = (int*)(ws + WS_INTS);
  const float* zs = (const float*)(ws + 128);       // zero-stub (16 B used)
  int* perm = (int*)(ws + WS_PERM);
  unsigned short* W1t = (unsigned short*)(ws + WS_W1T);
  unsigned short* W2t = (unsigned short*)(ws + WS_W2T);
  unsigned short* W3t = (unsigned short*)(ws + WS_W3T);
  unsigned short* W4t = (unsigned short*)(ws + WS_W4T);
  unsigned short* H1 = (unsigned short*)(ws + WS_H1);
  unsigned short* H2 = (unsigned short*)(ws + WS_H2);

  // species bucketing
  k_init<<<(MPAD + 255) / 256, 256, 0, stream>>>(ints, perm, out);
  k_count<<<NATOMS / 256, 256, 0, stream>>>(species, ints);
  k_offsets<<<1, 1, 0, stream>>>(ints);
  k_scatter<<<NATOMS / 256, 256, 0, stream>>>(species, ints, perm);

  // weight prep for layer 1 (W2/W3 transposed after L1 — they alias W1t)
  k_transpose<<<NSPEC * (NFEAT / 64) * (HIDDEN / 64), 256, 0, stream>>>(W1, W1t, NFEAT, HIDDEN);
  k_w4<<<NSPEC, 256, 0, stream>>>(W4, W4t);

  const float s1 = 1.f / sqrtf((float)NFEAT);
  const float s2 = 1.f / 16.f;

  // layer 1 (f32 gather -> bf16 MFMA)
  k_mlp<NFEAT, true><<<NBLKG, 256, 0, stream>>>(features, nullptr, W1t, H1, perm, ints + 8, zs, s1);

  // W2/W3 prep (W1t region now dead)
  k_transpose<<<NSPEC * (HIDDEN / 64) * (HIDDEN / 64), 256, 0, stream>>>(W2, W2t, HIDDEN, HIDDEN);
  k_transpose<<<NSPEC * (HIDDEN / 64) * (HIDDEN / 64), 256, 0, stream>>>(W3, W3t, HIDDEN, HIDDEN);

  // layers 2, 3
  k_mlp<HIDDEN, false><<<NBLKG, 256, 0, stream>>>(nullptr, H1, W2t, H2, perm, ints + 8, zs, s2);
  k_mlp<HIDDEN, false><<<NBLKG, 256, 0, stream>>>(nullptr, H2, W3t, H1, perm, ints + 8, zs, s2);

  // layer 4 + segment sum + composition term
  k_l4<<<MPAD / 4, 256, 0, stream>>>(H1, W4t, perm, species, sidx, coeff, out);
}